// Round 21
// baseline (8667.950 us; speedup 1.0000x reference)
//
#include <hip/hip_runtime.h>

#define T_STEPS 256
#define H_DIM   1024
#define L_CTX   200
#define CTXD    512
#define A_DIM   512
#define G4      4096
#define KT2     3072   // W4I k-range: 1024 Uh + 1024 Ph + 1024 Hh

// ws offsets (floats)
#define OFF_XWB    0                            // 256*4096 f32
#define OFF_CTXW   (OFF_XWB   + T_STEPS*G4)     // 200*512 f32
#define OFF_HIST   (OFF_CTXW  + L_CTX*A_DIM)    // 256*1024 f32 (write-once rows)
#define OFF_HWT    (OFF_HIST  + T_STEPS*H_DIM)  // histWT [512][256] f32
#define OFF_EPART  (OFF_HWT   + A_DIM*T_STEPS)  // [256][8][512] f32 partial logits
#define OFF_CC     (OFF_EPART + T_STEPS*8*512)  // bf16 4096*200
#define OFF_HH     (OFF_CC    + G4*L_CTX/2)     // bf16 4096*256 (col-owner private)
#define OFF_W4TI8  (OFF_HH    + G4*T_STEPS/2)   // int8 4096*3072
#define OFF_WSC    (OFF_W4TI8 + G4*KT2/4)       // 4096 f32
#define OFF_W3I8   (OFF_WSC   + G4)             // int8 1536*1024 rows [Wh|Whh|Whist]
#define OFF_WSC3   (OFF_W3I8  + 1536*H_DIM/4)   // 1536 f32
#define WS_FLOATS  (OFF_WSC3  + 1536)

__device__ __forceinline__ float sigmoidf_(float x) { return 1.f / (1.f + __expf(-x)); }
__device__ __forceinline__ float bf2f(unsigned short h) { return __uint_as_float((unsigned)h << 16); }
__device__ __forceinline__ unsigned short f2bf(float x) {
    unsigned u = __float_as_uint(x);
    return (unsigned short)((u + 0x7FFFu + ((u >> 16) & 1u)) >> 16);
}
__device__ __forceinline__ float wred(float x) {
    #pragma unroll
    for (int off = 32; off; off >>= 1) x += __shfl_down(x, off);
    return x;
}
__device__ __forceinline__ float wredmax(float x) {
    #pragma unroll
    for (int off = 32; off; off >>= 1) x = fmaxf(x, __shfl_down(x, off));
    return x;
}
#define DOT4(W, XP, ACC)                                            \
    { int wa_ = (int)(W);                                           \
      ACC += (float)((wa_ << 24) >> 24) * (XP)[0];                  \
      ACC += (float)((wa_ << 16) >> 24) * (XP)[1];                  \
      ACC += (float)((wa_ <<  8) >> 24) * (XP)[2];                  \
      ACC += (float)( wa_        >> 24) * (XP)[3]; }

// ---------- prep kernels ----------

__global__ __launch_bounds__(256) void k_xwb(const float* __restrict__ X,
                                             const float* __restrict__ Wx,
                                             const float* __restrict__ b4,
                                             float* __restrict__ XWb) {
    int c  = blockIdx.x * 256 + threadIdx.x;
    int r0 = blockIdx.y * 8;
    float acc[8] = {0,0,0,0,0,0,0,0};
    for (int k = 0; k < 512; ++k) {
        float wv = Wx[(size_t)k * G4 + c];
        #pragma unroll
        for (int r = 0; r < 8; ++r) acc[r] += X[(r0 + r) * 512 + k] * wv;
    }
    float bb = b4[c];
    #pragma unroll
    for (int r = 0; r < 8; ++r) XWb[(size_t)(r0 + r) * G4 + c] = acc[r] + bb;
}

__global__ __launch_bounds__(256) void k_ctxw(const float* __restrict__ ctx,
                                              const float* __restrict__ Wctx,
                                              const float* __restrict__ bctx,
                                              float* __restrict__ ctxW) {
    int a  = blockIdx.x * 256 + threadIdx.x;
    int l0 = blockIdx.y * 8;
    float acc[8] = {0,0,0,0,0,0,0,0};
    for (int k = 0; k < 512; ++k) {
        float wv = Wctx[(size_t)k * A_DIM + a];
        #pragma unroll
        for (int r = 0; r < 8; ++r) acc[r] += ctx[(l0 + r) * CTXD + k] * wv;
    }
    float bb = bctx[a];
    #pragma unroll
    for (int r = 0; r < 8; ++r) ctxW[(l0 + r) * A_DIM + a] = acc[r] + bb;
}

__global__ __launch_bounds__(256) void k_cc(const float* __restrict__ ctx,
                                            const float* __restrict__ Cc,
                                            unsigned short* __restrict__ CCp) {
    int c  = blockIdx.x * 256 + threadIdx.x;
    int l0 = blockIdx.y * 8;
    float acc[8] = {0,0,0,0,0,0,0,0};
    for (int k = 0; k < 512; ++k) {
        float wv = Cc[(size_t)k * G4 + c];
        #pragma unroll
        for (int r = 0; r < 8; ++r) acc[r] += ctx[(l0 + r) * CTXD + k] * wv;
    }
    int colp = 4 * (c & 1023) + (c >> 10);
    #pragma unroll
    for (int r = 0; r < 8; ++r) CCp[(size_t)colp * L_CTX + l0 + r] = f2bf(acc[r]);
}

__global__ __launch_bounds__(256) void k_colmax(const float* __restrict__ Uh,
                                                const float* __restrict__ Ph,
                                                const float* __restrict__ Hh,
                                                float* __restrict__ wsc) {
    int c = blockIdx.x * 256 + threadIdx.x;
    float m = 0.f;
    for (int k = 0; k < 1024; ++k) {
        m = fmaxf(m, fabsf(Uh[(size_t)k * G4 + c]));
        m = fmaxf(m, fabsf(Ph[(size_t)k * G4 + c]));
        m = fmaxf(m, fabsf(Hh[(size_t)k * G4 + c]));
    }
    int colp = 4 * (c & 1023) + (c >> 10);
    wsc[colp] = fmaxf(m, 1e-20f) / 127.f;
}

__global__ __launch_bounds__(256) void k_packW4i8(const float* __restrict__ Uh,
                                                  const float* __restrict__ Ph,
                                                  const float* __restrict__ Hh,
                                                  const float* __restrict__ wsc,
                                                  signed char* __restrict__ W8) {
    __shared__ float tile[32][33];
    const int k0 = blockIdx.x * 32, d0 = blockIdx.y * 32, q = blockIdx.z;
    const int x = threadIdx.x & 31, yy = threadIdx.x >> 5;
    const int c = q * 1024 + d0 + x;
    #pragma unroll
    for (int i = 0; i < 32; i += 8) {
        int ka = k0 + yy + i;
        const float* src; int kk;
        if (ka < 1024)      { src = Uh; kk = ka; }
        else if (ka < 2048) { src = Ph; kk = ka - 1024; }
        else                { src = Hh; kk = ka - 2048; }
        tile[yy + i][x] = src[(size_t)kk * G4 + c];
    }
    __syncthreads();
    #pragma unroll
    for (int i = 0; i < 32; i += 8) {
        int dd = yy + i;
        int col = 4 * (d0 + dd) + q;
        float r = 1.f / wsc[col];
        float qv = rintf(tile[x][dd] * r);
        qv = fminf(fmaxf(qv, -127.f), 127.f);
        W8[(size_t)col * KT2 + k0 + x] = (signed char)qv;
    }
}

__global__ __launch_bounds__(256) void k_w3max(const float* __restrict__ Wh,
                                               const float* __restrict__ Whh,
                                               const float* __restrict__ Whist,
                                               float* __restrict__ wsc3) {
    int c = blockIdx.x * 256 + threadIdx.x;
    const float* S = (blockIdx.y == 0) ? Wh : (blockIdx.y == 1) ? Whh : Whist;
    float m = 0.f;
    for (int k = 0; k < 1024; ++k) m = fmaxf(m, fabsf(S[(size_t)k * 512 + c]));
    wsc3[blockIdx.y * 512 + c] = fmaxf(m, 1e-20f) / 127.f;
}

__global__ __launch_bounds__(256) void k_packW3i8(const float* __restrict__ Wh,
                                                  const float* __restrict__ Whh,
                                                  const float* __restrict__ Whist,
                                                  const float* __restrict__ wsc3,
                                                  signed char* __restrict__ W3) {
    __shared__ float tile[32][33];
    const int k0 = blockIdx.x * 32, c0 = blockIdx.y * 32, s = blockIdx.z;
    const float* S = (s == 0) ? Wh : (s == 1) ? Whh : Whist;
    const int x = threadIdx.x & 31, yy = threadIdx.x >> 5;
    #pragma unroll
    for (int i = 0; i < 32; i += 8)
        tile[yy + i][x] = S[(size_t)(k0 + yy + i) * 512 + c0 + x];
    __syncthreads();
    #pragma unroll
    for (int i = 0; i < 32; i += 8) {
        int dd = yy + i;
        int row = s * 512 + c0 + dd;
        float r = 1.f / wsc3[row];
        float qv = rintf(tile[x][dd] * r);
        qv = fminf(fmaxf(qv, -127.f), 127.f);
        W3[(size_t)row * H_DIM + k0 + x] = (signed char)qv;
    }
}

// ---------- per-step kernels ----------

struct SP {
    const float *ctx, *c0, *v, *v2, *bv, *bv2, *bhist, *h0;
    const int* parent;
    float* ws;
    float* out;
};

// K1: 16 blocks. Block g owns dims [64g,64g+64) of [u|w]; computes slice via
// int8 rows, then PARTIAL logits for its slice -> epart[t][g'][...].
__global__ __launch_bounds__(512) void k_step1(SP p, int t) {
    const int g   = blockIdx.x;          // [0,16)
    const int tid = threadIdx.x;
    const int lane = tid & 63, wv = tid >> 6;

    float* hist   = p.ws + OFF_HIST;
    float* histWT = p.ws + OFF_HWT;
    float* epart  = p.ws + OFF_EPART + (size_t)t * 4096;
    const float* ctxW = p.ws + OFF_CTXW;
    const unsigned char* W3I = (const unsigned char*)(p.ws + OFF_W3I8);
    const float* WSC3 = p.ws + OFF_WSC3;

    __shared__ float xs[1024];
    __shared__ float uwl[64];     // this block's slice of u or w
    __shared__ float hwl[64];     // w-blocks: own histW slice of row t-1

    const float* hprev = (t == 0) ? p.h0 : hist + (size_t)(t - 1) * H_DIM;
    xs[tid] = hprev[tid];
    if (tid < 512) xs[512 + tid] = hprev[512 + tid];
    __syncthreads();

    const int r = tid >> 3, sub = tid & 7;    // 64 rows x 8 subs

    // main slice dot (row = g*64 + r)
    {
        const int row = g * 64 + r;
        const uint4* wp = (const uint4*)(W3I + (size_t)row * H_DIM);
        float a = 0.f;
        #pragma unroll
        for (int i = 0; i < 8; ++i) {
            uint4 q = wp[sub * 8 + i];
            const float* x = xs + (sub * 8 + i) * 16;
            DOT4(q.x, x, a); DOT4(q.y, x + 4, a);
            DOT4(q.z, x + 8, a); DOT4(q.w, x + 12, a);
        }
        a += __shfl_down(a, 4, 8);
        a += __shfl_down(a, 2, 8);
        a += __shfl_down(a, 1, 8);
        if (sub == 0) {
            float val = a * WSC3[row];
            if (row >= A_DIM) val += p.bhist[row - A_DIM];
            uwl[r] = val;
        }
    }
    // histWT global write: rows 1024 + 32g + r (r<32), col t-1
    if (t >= 1 && r < 32) {
        const int row = 1024 + g * 32 + r;
        const uint4* wp = (const uint4*)(W3I + (size_t)row * H_DIM);
        float a = 0.f;
        #pragma unroll
        for (int i = 0; i < 8; ++i) {
            uint4 q = wp[sub * 8 + i];
            const float* x = xs + (sub * 8 + i) * 16;
            DOT4(q.x, x, a); DOT4(q.y, x + 4, a);
            DOT4(q.z, x + 8, a); DOT4(q.w, x + 12, a);
        }
        a += __shfl_down(a, 4, 8);
        a += __shfl_down(a, 2, 8);
        a += __shfl_down(a, 1, 8);
        if (sub == 0) histWT[(size_t)(g * 32 + r) * T_STEPS + (t - 1)] = a * WSC3[row];
    }
    // w-blocks: own histW slice of row t-1 into LDS (for j = t-1 partial)
    if (t >= 1 && g >= 8) {
        const int row = 1024 + (g - 8) * 64 + r;
        const uint4* wp = (const uint4*)(W3I + (size_t)row * H_DIM);
        float a = 0.f;
        #pragma unroll
        for (int i = 0; i < 8; ++i) {
            uint4 q = wp[sub * 8 + i];
            const float* x = xs + (sub * 8 + i) * 16;
            DOT4(q.x, x, a); DOT4(q.y, x + 4, a);
            DOT4(q.z, x + 8, a); DOT4(q.w, x + 12, a);
        }
        a += __shfl_down(a, 4, 8);
        a += __shfl_down(a, 2, 8);
        a += __shfl_down(a, 1, 8);
        if (sub == 0) hwl[r] = a * WSC3[row];
    }
    __syncthreads();

    // partial logits for this slice
    if (g < 8) {
        const int d = g * 64 + lane;               // u-dim
        const float uv = uwl[lane], vv = p.v[d];
        for (int l = wv; l < L_CTX; l += 8) {
            float e = tanhf(ctxW[(size_t)l * A_DIM + d] + uv) * vv;
            e = wred(e);
            if (lane == 0) epart[g * 512 + l] = e;
        }
    } else if (t >= 1) {
        const int d2 = (g - 8) * 64 + lane;        // w-dim
        const float wvv = uwl[lane], v2v = p.v2[d2];
        const float* hwrow = histWT + (size_t)d2 * T_STEPS;
        for (int j = wv; j < t; j += 8) {
            float hval = (j == t - 1) ? hwl[lane] : hwrow[j];
            float e = tanhf(hval + wvv) * v2v;
            e = wred(e);
            if (lane == 0) epart[(g - 8) * 512 + 256 + j] = e;
        }
    }
}

// K2: 256 blocks x 512 thr. Block b owns permuted cols [16b,16b+16) = h-dims
// [4b,4b+4). Partial-sum logits -> softmax (replicated) -> z -> gates -> h_t.
__global__ __launch_bounds__(512) void k_step2(SP p, int t) {
    const int b   = blockIdx.x;          // [0,256)
    const int tid = threadIdx.x;
    const int lane = tid & 63, wv = tid >> 6;

    float* XWb  = p.ws + OFF_XWB;
    float* hist = p.ws + OFF_HIST;
    const float* epart = p.ws + OFF_EPART + (size_t)t * 4096;
    const unsigned short* CCp = (const unsigned short*)(p.ws + OFF_CC);
    unsigned short*       HHp = (unsigned short*)(p.ws + OFF_HH);
    const unsigned char*  W4I = (const unsigned char*)(p.ws + OFF_W4TI8);
    const float*          WSC = p.ws + OFF_WSC;

    __shared__ float xs[2048];
    __shared__ float aC[256], aH[256];
    __shared__ float red[16], sc[4], zsl[16];

    // stage h_{t-1} and parent row
    {
        const float* hprev = (t == 0) ? p.h0 : hist + (size_t)(t - 1) * H_DIM;
        float hv0 = hprev[tid], hv1 = hprev[512 + tid];
        xs[tid] = hv0; xs[512 + tid] = hv1;
        if (t == 0) { xs[1024 + tid] = 0.f; xs[1536 + tid] = 0.f; }
        else {
            const int pt = p.parent[t];
            if (pt == t - 1) { xs[1024 + tid] = hv0; xs[1536 + tid] = hv1; }
            else {
                const float* pr = hist + (size_t)pt * H_DIM;
                xs[1024 + tid] = pr[tid]; xs[1536 + tid] = pr[512 + tid];
            }
        }
    }
    // sum partial logits
    if (tid < L_CTX) {
        float s = p.bv[0];
        #pragma unroll
        for (int g = 0; g < 8; ++g) s += epart[g * 512 + tid];
        aC[tid] = s;
    }
    if (tid < t) {
        float s = p.bv2[0];
        #pragma unroll
        for (int g = 0; g < 8; ++g) s += epart[g * 512 + 256 + tid];
        aH[tid] = s;
    }
    __syncthreads();

    // replicated softmax
    {
        float pC = (tid < L_CTX) ? aC[tid] : -3e38f;
        float pH = (tid < t)     ? aH[tid] : -3e38f;
        pC = wredmax(pC); pH = wredmax(pH);
        if (lane == 0) { red[wv] = pC; red[8 + wv] = pH; }
        __syncthreads();
        if (tid == 0) { float m = -3e38f; for (int g = 0; g < 8; ++g) m = fmaxf(m, red[g]); sc[0] = m; }
        if (tid == 1) { float m = -3e38f; for (int g = 0; g < 8; ++g) m = fmaxf(m, red[8 + g]); sc[1] = m; }
        __syncthreads();
        const float mC = sc[0], mH = sc[1];
        float sCp = 0.f, sHp = 0.f;
        if (tid < L_CTX) { float x = __expf(aC[tid] - mC); aC[tid] = x; sCp = x; }
        if (tid < t)     { float x = __expf(aH[tid] - mH); aH[tid] = x; sHp = x; }
        sCp = wred(sCp); sHp = wred(sHp);
        if (lane == 0) { red[wv] = sCp; red[8 + wv] = sHp; }
        __syncthreads();
        if (tid == 0) { float s = 0.f; for (int g = 0; g < 8; ++g) s += red[g]; sc[2] = s; }
        if (tid == 1) { float s = 0.f; for (int g = 0; g < 8; ++g) s += red[8 + g]; sc[3] = s; }
        __syncthreads();
    }
    const float rC = 1.f / sc[2];
    const float rH = (t > 0) ? 1.f / sc[3] : 0.f;

    // per-col work: col = tid>>5 (16 cols), sub = tid&31
    const int col = tid >> 5, sub = tid & 31;
    const int gcol = b * 16 + col;
    const uint2* Wcol = (const uint2*)(W4I + (size_t)gcol * KT2);
    const float  wscl = WSC[gcol];
    const unsigned short* ccC = CCp + (size_t)gcol * L_CTX;
    unsigned short*       hhC = HHp + (size_t)gcol * T_STEPS;

    // hh[col][t-1] = h_{t-1} . Hh[:,col]
    if (t >= 1) {
        float a = 0.f;
        #pragma unroll
        for (int i = 0; i < 4; ++i) {
            const int c2 = 256 + sub * 4 + i;     // Hh uint2 range [256,384)
            uint2 w = Wcol[c2];
            const float* xk = xs + (c2 - 256) * 8;
            DOT4(w.x, xk, a); DOT4(w.y, xk + 4, a);
        }
        #pragma unroll
        for (int off = 16; off; off >>= 1) a += __shfl_down(a, off, 32);
        if (sub == 0) hhC[t - 1] = f2bf(a * wscl);
    }
    __syncthreads();

    // z = int8(Uh,Ph over [h|par]) * scale + attn(cc,hh)
    {
        float g0 = 0.f, g1 = 0.f;
        #pragma unroll
        for (int i = 0; i < 8; ++i) {
            const int c2 = sub * 8 + i;           // [0,256) uint2 = k<2048
            uint2 w = Wcol[c2];
            const float* xk = xs + c2 * 8;
            DOT4(w.x, xk, g0); DOT4(w.y, xk + 4, g1);
        }
        float acc = (g0 + g1) * wscl;
        float attc = 0.f, atth = 0.f;
        for (int l = sub; l < L_CTX; l += 32) attc += aC[l] * bf2f(ccC[l]);
        for (int j = sub; j < t; j += 32)     atth += aH[j] * bf2f(hhC[j]);
        acc += attc * rC + atth * rH;
        #pragma unroll
        for (int off = 16; off; off >>= 1) acc += __shfl_down(acc, off, 32);
        if (sub == 0) zsl[col] = acc;
    }
    __syncthreads();
    if (tid < 4) {
        const int d = b * 4 + tid;
        float zi = zsl[4 * tid + 0] + XWb[(size_t)t * G4 + 0 * 1024 + d];
        float zf = zsl[4 * tid + 1] + XWb[(size_t)t * G4 + 1 * 1024 + d];
        float zc = zsl[4 * tid + 2] + XWb[(size_t)t * G4 + 2 * 1024 + d];
        float zo = zsl[4 * tid + 3] + XWb[(size_t)t * G4 + 3 * 1024 + d];
        float cn = sigmoidf_(zf) * p.c0[d] + sigmoidf_(zi) * tanhf(zc);
        float hn = sigmoidf_(zo) * tanhf(cn);
        hist[(size_t)t * H_DIM + d] = hn;
        p.out[(size_t)t * H_DIM + d] = hn;
    }
    // out_ctx: 2 dims per block (d = 2b + wv for wv<2)
    if (wv < 2) {
        const int d = b * 2 + wv;
        float s = 0.f;
        for (int l = lane; l < L_CTX; l += 64)
            s += aC[l] * p.ctx[(size_t)l * CTXD + d];
        s = wred(s);
        if (lane == 0)
            p.out[(size_t)T_STEPS * H_DIM + (size_t)t * CTXD + d] = s * rC;
    }
}

// ---------- host ----------

extern "C" void kernel_launch(void* const* d_in, const int* in_sizes, int n_in,
                              void* d_out, int out_size, void* d_ws, size_t ws_size,
                              hipStream_t stream) {
    if (ws_size < (size_t)WS_FLOATS * sizeof(float)) return;  // OOB insurance

    const float* X      = (const float*)d_in[0];
    const float* ctx    = (const float*)d_in[1];
    const float* h0     = (const float*)d_in[2];
    const float* c0     = (const float*)d_in[3];
    const int*   parent = (const int*)  d_in[4];
    const float* Wx     = (const float*)d_in[5];
    const float* Uh     = (const float*)d_in[6];
    const float* Cc     = (const float*)d_in[7];
    const float* Ph     = (const float*)d_in[8];
    const float* Hh     = (const float*)d_in[9];
    const float* b4     = (const float*)d_in[10];
    const float* Wctx   = (const float*)d_in[11];
    const float* bctx   = (const float*)d_in[12];
    const float* Wh     = (const float*)d_in[13];
    const float* v      = (const float*)d_in[14];
    const float* bv     = (const float*)d_in[15];
    const float* Whist  = (const float*)d_in[16];
    const float* bhist  = (const float*)d_in[17];
    const float* Whh    = (const float*)d_in[18];
    const float* v2     = (const float*)d_in[19];
    const float* bv2    = (const float*)d_in[20];
    float* ws  = (float*)d_ws;
    float* out = (float*)d_out;

    hipLaunchKernelGGL(k_xwb,      dim3(16, 32),    dim3(256), 0, stream, X,   Wx,   b4,   ws + OFF_XWB);
    hipLaunchKernelGGL(k_ctxw,     dim3(2, 25),     dim3(256), 0, stream, ctx, Wctx, bctx, ws + OFF_CTXW);
    hipLaunchKernelGGL(k_cc,       dim3(16, 25),    dim3(256), 0, stream, ctx, Cc,
                       (unsigned short*)(ws + OFF_CC));
    hipLaunchKernelGGL(k_colmax,   dim3(16),        dim3(256), 0, stream, Uh, Ph, Hh, ws + OFF_WSC);
    hipLaunchKernelGGL(k_packW4i8, dim3(96, 32, 4), dim3(256), 0, stream, Uh, Ph, Hh,
                       ws + OFF_WSC, (signed char*)(ws + OFF_W4TI8));
    hipLaunchKernelGGL(k_w3max,    dim3(2, 3),      dim3(256), 0, stream, Wh, Whh, Whist, ws + OFF_WSC3);
    hipLaunchKernelGGL(k_packW3i8, dim3(32, 16, 3), dim3(256), 0, stream, Wh, Whh, Whist,
                       ws + OFF_WSC3, (signed char*)(ws + OFF_W3I8));

    SP p{ctx, c0, v, v2, bv, bv2, bhist, h0, parent, ws, out};
    for (int t = 0; t < T_STEPS; ++t) {
        hipLaunchKernelGGL(k_step1, dim3(16),  dim3(512), 0, stream, p, t);
        hipLaunchKernelGGL(k_step2, dim3(256), dim3(512), 0, stream, p, t);
    }
}